// Round 3
// baseline (86.539 us; speedup 1.0000x reference)
//
#include <hip/hip_runtime.h>

// out = ((x@W1.T+b1)@W2.T+b2)@W3.T+b3 ; exilu == identity (tautological mask)
// => single affine map: out = x @ Wc.T + bc, Wc = W3@W2@W1 [6,6], bc [6].
// B = 8388608 rows x 6 fp32. 402 MB traffic -> ~64 us floor at 6.3 TB/s copy ceiling.
//
// Single fused kernel:
//  - each thread folds its 3 needed rows of Wc/bc from W1..b3 (~420 indep FMAs,
//    one-time, hidden under the first memory latency; weights are L2-resident).
//  - stream loop: lane pair (2j,2j+1) owns row j; lane i handles floats [3i,3i+3)
//    -> 12B lane stride, fully unit-stride dwordx3 loads/stores.
//  - ILP-2: two independent units (u, u+T) per iteration -> 2x bytes in flight.

struct __align__(4) F3 { float a, b, c; };

__global__ void __launch_bounds__(256) mlp_fused(const float* __restrict__ x,
                                                 const float* __restrict__ W1,
                                                 const float* __restrict__ b1,
                                                 const float* __restrict__ W2,
                                                 const float* __restrict__ b2,
                                                 const float* __restrict__ W3,
                                                 const float* __restrict__ b3,
                                                 float* __restrict__ out,
                                                 int nUnits) {
    const int tid = blockIdx.x * blockDim.x + threadIdx.x;
    const int T   = gridDim.x * blockDim.x;
    const int par = threadIdx.x & 1;  // 0: out floats 0-2, 1: out floats 3-5

    // ---- per-thread fold: rows [3*par, 3*par+3) of Wc = (W3@W2)@W1, bc ----
    // bb = W2@b1 + b2 (uniform -> scalar-load friendly)
    float bb[8];
#pragma unroll
    for (int o = 0; o < 8; ++o) {
        float s = b2[o];
#pragma unroll
        for (int k = 0; k < 8; ++k) s = fmaf(W2[o * 8 + k], b1[k], s);
        bb[o] = s;
    }

    float w[3][6], bs[3];
#pragma unroll
    for (int r = 0; r < 3; ++r) {
        const int row = 3 * par + r;
        // v = W3[row, :] (8)
        float v[8];
#pragma unroll
        for (int k = 0; k < 8; ++k) v[k] = W3[row * 8 + k];
        // u = v @ W2 (8)
        float u[8];
#pragma unroll
        for (int k2 = 0; k2 < 8; ++k2) {
            float s = 0.f;
#pragma unroll
            for (int k = 0; k < 8; ++k) s = fmaf(v[k], W2[k * 8 + k2], s);
            u[k2] = s;
        }
        // w[r] = u @ W1 (6)
#pragma unroll
        for (int i = 0; i < 6; ++i) {
            float s = 0.f;
#pragma unroll
            for (int k = 0; k < 8; ++k) s = fmaf(u[k], W1[k * 6 + i], s);
            w[r][i] = s;
        }
        // bs[r] = v @ bb + b3[row]
        float s = b3[row];
#pragma unroll
        for (int k = 0; k < 8; ++k) s = fmaf(v[k], bb[k], s);
        bs[r] = s;
    }

    const F3* __restrict__ xv = reinterpret_cast<const F3*>(x);
    F3* __restrict__       ov = reinterpret_cast<F3*>(out);

    // ---- stream loop, ILP-2 ----
    for (int u0 = tid; u0 < nUnits; u0 += 2 * T) {
        const int u1 = u0 + T;
        const bool has1 = (u1 < nUnits);

        F3 a = xv[u0];
        F3 b = has1 ? xv[u1] : F3{0.f, 0.f, 0.f};

        // partner halves via lane^1 quad-perm shuffles
        float pa0 = __shfl_xor(a.a, 1), pb0 = __shfl_xor(a.b, 1), pc0 = __shfl_xor(a.c, 1);
        float pa1 = __shfl_xor(b.a, 1), pb1 = __shfl_xor(b.b, 1), pc1 = __shfl_xor(b.c, 1);

        float x0[6], x1[6];
        x0[0] = par ? pa0 : a.a;  x0[1] = par ? pb0 : a.b;  x0[2] = par ? pc0 : a.c;
        x0[3] = par ? a.a : pa0;  x0[4] = par ? a.b : pb0;  x0[5] = par ? a.c : pc0;
        x1[0] = par ? pa1 : b.a;  x1[1] = par ? pb1 : b.b;  x1[2] = par ? pc1 : b.c;
        x1[3] = par ? b.a : pa1;  x1[4] = par ? b.b : pb1;  x1[5] = par ? b.c : pc1;

        F3 o0, o1;
        float* q0 = &o0.a;
        float* q1 = &o1.a;
#pragma unroll
        for (int r = 0; r < 3; ++r) {
            float s0 = bs[r], s1 = bs[r];
#pragma unroll
            for (int i = 0; i < 6; ++i) {
                s0 = fmaf(w[r][i], x0[i], s0);
                s1 = fmaf(w[r][i], x1[i], s1);
            }
            q0[r] = s0;
            q1[r] = s1;
        }
        ov[u0] = o0;
        if (has1) ov[u1] = o1;
    }
}

extern "C" void kernel_launch(void* const* d_in, const int* in_sizes, int n_in,
                              void* d_out, int out_size, void* d_ws, size_t ws_size,
                              hipStream_t stream) {
    const float* x  = (const float*)d_in[0];
    const float* W1 = (const float*)d_in[1];
    const float* b1 = (const float*)d_in[2];
    const float* W2 = (const float*)d_in[3];
    const float* b2 = (const float*)d_in[4];
    const float* W3 = (const float*)d_in[5];
    const float* b3 = (const float*)d_in[6];
    float* outp = (float*)d_out;

    int nUnits = in_sizes[0] / 3;  // 16777216 dwordx3 units (2 per row)
    int blocks = 2048;             // 8 blocks/CU; 16 ILP-2 iterations/thread
    mlp_fused<<<blocks, 256, 0, stream>>>(x, W1, b1, W2, b2, W3, b3, outp, nUnits);
}